// Round 5
// baseline (137.024 us; speedup 1.0000x reference)
//
#include <hip/hip_runtime.h>
#include <math.h>

// Problem constants (match reference)
#define BGRAPH 64
#define N_PER  1024
#define KSEL   512
#define NTOT   65536       // BGRAPH * N_PER
#define EDG    2097152
#define FIN    256
#define FE     16

// Native clang vector type: __builtin_nontemporal_* requires a true vector
// type, not HIP's float4 struct (R3 lesson).
typedef float v4f __attribute__((ext_vector_type(4)));

// d_out flat layout (float32 elements), reference tuple order:
#define OFF_XOUT   0
#define OFF_EI     8388608
#define OFF_EA     12582912
#define OFF_BATCH  46137344
#define OFF_PERM   46170112
#define OFF_SCORE  46202880
#define OFF_EMASK  46268416

// d_ws layout: [0,256KB) node_map (int[65536]); [256KB,768KB) dots (double[65536])
#define WS_DOTS_OFF 65536   // in ints

// ---------------------------------------------------------------------------
// Kernel 1: z = dot(x[n],W)+b in f64 (rank key, matches np-f64 ordering —
// known good: absmax 128 << 1310 across 3 passes). Output score = tanhf(z):
// tanh is strictly monotone so ranking by z == ranking by tanh(z); the f32
// tanh only affects the VALUE outputs (threshold 4%, tanhf err ~1e-7).
// This removes the f64 tanh LIBCALL (~150 f64 VALU ops/wave) that made this
// kernel VALU-bound instead of BW-bound.
__global__ __launch_bounds__(256) void score_kernel(
    const float* __restrict__ x, const float* __restrict__ W,
    const float* __restrict__ bptr, float* __restrict__ score_out,
    double* __restrict__ dot_out) {
  int wave = threadIdx.x >> 6;
  int lane = threadIdx.x & 63;
  int node = blockIdx.x * 4 + wave;
  const float4* xr = reinterpret_cast<const float4*>(x + (size_t)node * FIN);
  const float4* wr = reinterpret_cast<const float4*>(W);
  float4 xv = xr[lane];
  float4 wv = wr[lane];
  double p = (double)xv.x * (double)wv.x + (double)xv.y * (double)wv.y +
             (double)xv.z * (double)wv.z + (double)xv.w * (double)wv.w;
#pragma unroll
  for (int off = 32; off >= 1; off >>= 1) p += __shfl_xor(p, off, 64);
  if (lane == 0) {
    double z = p + (double)bptr[0];
    dot_out[node]   = z;
    score_out[node] = tanhf((float)z);   // MULTIPLIER == 1.0
  }
}

// ---------------------------------------------------------------------------
// Kernel 2: per-graph bitonic sort of 1024 (f64 dot, idx) pairs.
// Hybrid: j<=32 phases via __shfl_xor (no barrier), j>=64 via LDS (2
// barriers). Final order: descending key, ties ascending index.
__global__ __launch_bounds__(1024) void topk_kernel(
    const double* __restrict__ dots, float* __restrict__ perm_out,
    float* __restrict__ batch_out, int* __restrict__ node_map) {
  __shared__ double sk[N_PER];
  __shared__ int    si[N_PER];
  int b = blockIdx.x;
  int t = threadIdx.x;
  int base = b * N_PER;
  double key = dots[base + t];
  int    idx = t;
  node_map[base + t] = -1;   // block owns exactly its graph's slice
  for (int k = 2; k <= N_PER; k <<= 1) {
    for (int j = k >> 1; j > 0; j >>= 1) {
      bool lower = (t & j) == 0;
      bool dirUp = (t & k) == 0;
      double okey; int oidx;
      if (j >= 64) {
        sk[t] = key; si[t] = idx;
        __syncthreads();
        okey = sk[t ^ j]; oidx = si[t ^ j];
        __syncthreads();
      } else {
        okey = __shfl_xor(key, j, 64);
        oidx = __shfl_xor(idx, j, 64);
      }
      bool own_prec = (key > okey) || (key == okey && idx < oidx);
      bool want_prec = (lower == dirUp);
      if (own_prec != want_prec) { key = okey; idx = oidx; }
    }
  }
  if (t < KSEL) {
    int g   = base + idx;          // global node id
    int gid = b * KSEL + t;        // remapped id (rank order)
    perm_out[gid]  = (float)g;
    __builtin_nontemporal_store((float)b, batch_out + gid);
    node_map[g]    = gid;
  }
}

// ---------------------------------------------------------------------------
// Kernel 3 (fused gather + edge): gather and edge are independent after topk;
// interleave them (odd blocks gather, even blocks edge) so both memory
// streams share the machine and one serialization point disappears.
__global__ __launch_bounds__(256) void tail_kernel(
    const float* __restrict__ x, const float* __restrict__ perm_f,
    const float* __restrict__ score, float* __restrict__ xout,
    const int* __restrict__ ei, const int* __restrict__ node_map,
    const float* __restrict__ ea, float* __restrict__ ei_out,
    float* __restrict__ emask_out, float* __restrict__ ea_out) {
  __shared__ float smask[256];
  int bid = blockIdx.x;
  int t = threadIdx.x;
  if (bid & 1) {
    // ---- gather: 4 rows of x_out ----
    int wave = t >> 6, lane = t & 63;
    int r = (bid >> 1) * 4 + wave;
    int g = (int)perm_f[r];           // exact (<= 65535)
    float s = score[g];
    const v4f* xr = reinterpret_cast<const v4f*>(x + (size_t)g * FIN);
    v4f v = __builtin_nontemporal_load(xr + lane);
    v4f o = v * s;
    __builtin_nontemporal_store(o, reinterpret_cast<v4f*>(xout + (size_t)r * FIN) + lane);
  } else {
    // ---- edge: 256 edges (mask/remap + attr copy) ----
    int e0 = (bid >> 1) * 256;
    int e = e0 + t;
    int r = __builtin_nontemporal_load(ei + e);
    int c = __builtin_nontemporal_load(ei + EDG + e);
    int nr = node_map[r];
    int nc = node_map[c];
    bool m = (nr >= 0) && (nc >= 0);
    __builtin_nontemporal_store(m ? (float)nr : -1.0f, ei_out + e);
    __builtin_nontemporal_store(m ? (float)nc : -1.0f, ei_out + EDG + e);
    float mf = m ? 1.0f : 0.0f;
    __builtin_nontemporal_store(mf, emask_out + e);
    smask[t] = mf;
    __syncthreads();
    const v4f* ea4 = reinterpret_cast<const v4f*>(ea) + (size_t)e0 * 4;
    v4f*      out4 = reinterpret_cast<v4f*>(ea_out)   + (size_t)e0 * 4;
#pragma unroll
    for (int q = 0; q < 4; ++q) {
      int fi = q * 256 + t;                 // local float4 index in [0,1024)
      float mm = smask[fi >> 2];
      v4f v = (v4f)(0.0f);
      if (mm != 0.0f) v = __builtin_nontemporal_load(ea4 + fi);
      __builtin_nontemporal_store(v, out4 + fi);
    }
  }
}

// ---------------------------------------------------------------------------
extern "C" void kernel_launch(void* const* d_in, const int* in_sizes, int n_in,
                              void* d_out, int out_size, void* d_ws, size_t ws_size,
                              hipStream_t stream) {
  const float* x  = (const float*)d_in[0];
  const int*   ei = (const int*)d_in[1];
  const float* ea = (const float*)d_in[2];
  // d_in[3] = batch (unused: graphs contiguous & equal size)
  const float* W  = (const float*)d_in[4];
  const float* bb = (const float*)d_in[5];

  float* out       = (float*)d_out;
  float* xout      = out + OFF_XOUT;
  float* ei_out    = out + OFF_EI;
  float* ea_out    = out + OFF_EA;
  float* batch_out = out + OFF_BATCH;
  float* perm_out  = out + OFF_PERM;
  float* score_out = out + OFF_SCORE;
  float* emask_out = out + OFF_EMASK;

  int*    node_map = (int*)d_ws;                         // 256 KB
  double* dots     = (double*)((int*)d_ws + WS_DOTS_OFF); // 512 KB @ +256KB

  score_kernel <<<NTOT / 4, 256, 0, stream>>>(x, W, bb, score_out, dots);
  topk_kernel  <<<BGRAPH, 1024, 0, stream>>>(dots, perm_out, batch_out, node_map);
  tail_kernel  <<<16384, 256, 0, stream>>>(x, perm_out, score_out, xout,
                                           ei, node_map, ea, ei_out, emask_out, ea_out);
}

// Round 6
// 112.446 us; speedup vs baseline: 1.2186x; 1.2186x over previous
//
#include <hip/hip_runtime.h>
#include <math.h>

// Problem constants (match reference)
#define BGRAPH 64
#define N_PER  1024
#define KSEL   512
#define NTOT   65536       // BGRAPH * N_PER
#define EDG    2097152
#define FIN    256
#define FE     16

// d_out flat layout (float32 elements), reference tuple order:
#define OFF_XOUT   0
#define OFF_EI     8388608
#define OFF_EA     12582912
#define OFF_BATCH  46137344
#define OFF_PERM   46170112
#define OFF_SCORE  46202880
#define OFF_EMASK  46268416

// d_ws layout: [0,256KB) node_map (int[65536]); [256KB,768KB) dots (double[65536])
#define WS_DOTS_OFF 65536   // in ints

// ---------------------------------------------------------------------------
// Kernel 1: z = dot(x[n],W)+b in f64 (rank key — must match np-f64 ordering;
// verified absmax 128 << 1310 across 4 passes). Value output via f32 tanhf:
// tanh is strictly monotone, so ranking by z == ranking by tanh(z); tanhf
// error (~1e-7) only touches VALUE outputs (4% threshold). Avoids the f64
// tanh libcall that made this kernel VALU-bound (R5 ledger: ~40 -> ~12 us).
__global__ __launch_bounds__(256) void score_kernel(
    const float* __restrict__ x, const float* __restrict__ W,
    const float* __restrict__ bptr, float* __restrict__ score_out,
    double* __restrict__ dot_out) {
  int wave = threadIdx.x >> 6;
  int lane = threadIdx.x & 63;
  int node = blockIdx.x * 4 + wave;
  const float4* xr = reinterpret_cast<const float4*>(x + (size_t)node * FIN);
  const float4* wr = reinterpret_cast<const float4*>(W);
  float4 xv = xr[lane];
  float4 wv = wr[lane];
  double p = (double)xv.x * (double)wv.x + (double)xv.y * (double)wv.y +
             (double)xv.z * (double)wv.z + (double)xv.w * (double)wv.w;
#pragma unroll
  for (int off = 32; off >= 1; off >>= 1) p += __shfl_xor(p, off, 64);
  if (lane == 0) {
    double z = p + (double)bptr[0];
    dot_out[node]   = z;
    score_out[node] = tanhf((float)z);   // MULTIPLIER == 1.0
  }
}

// ---------------------------------------------------------------------------
// Kernel 2: per-graph bitonic sort of 1024 (f64 dot, idx) pairs.
// Hybrid: j<=32 phases via __shfl_xor (no barrier), j>=64 via LDS (2
// barriers). Final order: descending key, ties ascending index (lax.top_k).
__global__ __launch_bounds__(1024) void topk_kernel(
    const double* __restrict__ dots, float* __restrict__ perm_out,
    float* __restrict__ batch_out, int* __restrict__ node_map) {
  __shared__ double sk[N_PER];
  __shared__ int    si[N_PER];
  int b = blockIdx.x;
  int t = threadIdx.x;
  int base = b * N_PER;
  double key = dots[base + t];
  int    idx = t;
  node_map[base + t] = -1;   // block owns exactly its graph's slice
  for (int k = 2; k <= N_PER; k <<= 1) {
    for (int j = k >> 1; j > 0; j >>= 1) {
      bool lower = (t & j) == 0;
      bool dirUp = (t & k) == 0;
      double okey; int oidx;
      if (j >= 64) {
        sk[t] = key; si[t] = idx;
        __syncthreads();
        okey = sk[t ^ j]; oidx = si[t ^ j];
        __syncthreads();
      } else {
        okey = __shfl_xor(key, j, 64);
        oidx = __shfl_xor(idx, j, 64);
      }
      bool own_prec = (key > okey) || (key == okey && idx < oidx);
      bool want_prec = (lower == dirUp);
      if (own_prec != want_prec) { key = okey; idx = oidx; }
    }
  }
  if (t < KSEL) {
    int g   = base + idx;          // global node id
    int gid = b * KSEL + t;        // remapped id (rank order)
    perm_out[gid]  = (float)g;
    batch_out[gid] = (float)b;
    node_map[g]    = gid;
  }
}

// ---------------------------------------------------------------------------
// Kernel 3: x_out[r] = x[perm[r]] * score[perm[r]]. One wave per row.
// Plain loads: x is L3-resident from score_kernel's pass (256 MB L3, x=64MB),
// so these gathers mostly hit L3. Plain stores: L2 write-combining.
__global__ __launch_bounds__(256) void gather_kernel(
    const float* __restrict__ x, const float* __restrict__ perm_f,
    const float* __restrict__ score, float* __restrict__ xout) {
  int wave = threadIdx.x >> 6;
  int lane = threadIdx.x & 63;
  int r = blockIdx.x * 4 + wave;
  int g = (int)perm_f[r];           // exact (<= 65535)
  float s = score[g];
  float4 v = reinterpret_cast<const float4*>(x + (size_t)g * FIN)[lane];
  float4 o;
  o.x = v.x * s; o.y = v.y * s; o.z = v.z * s; o.w = v.w * s;
  reinterpret_cast<float4*>(xout + (size_t)r * FIN)[lane] = o;
}

// ---------------------------------------------------------------------------
// Kernel 4: edge mask/remap + attr copy, 256 edges per block.
// Phase 1: thread-per-edge, coalesced ei reads, mask to LDS + outputs.
// Phase 2: 4 coalesced float4 passes over edge_attr; read predicated on mask
// (64 B line == 1 edge, 25% keep rate -> ~75% of the 128 MB read skipped);
// write always (output buffer is poisoned). All PLAIN loads/stores — R5
// showed the NT-hinted version capped at 2.28 TB/s; normal stores
// write-combine in L2 (fill kernel proves 6.9 TB/s that way).
__global__ __launch_bounds__(256) void edge_kernel(
    const int* __restrict__ ei, const int* __restrict__ node_map,
    const float* __restrict__ ea, float* __restrict__ ei_out,
    float* __restrict__ emask_out, float* __restrict__ ea_out) {
  __shared__ float smask[256];
  int t = threadIdx.x;
  int e0 = blockIdx.x * 256;
  int e = e0 + t;
  int r = ei[e];
  int c = ei[EDG + e];
  int nr = node_map[r];
  int nc = node_map[c];
  bool m = (nr >= 0) && (nc >= 0);
  ei_out[e]       = m ? (float)nr : -1.0f;
  ei_out[EDG + e] = m ? (float)nc : -1.0f;
  float mf = m ? 1.0f : 0.0f;
  emask_out[e] = mf;
  smask[t]     = mf;
  __syncthreads();
  const float4* ea4 = reinterpret_cast<const float4*>(ea) + (size_t)e0 * 4;
  float4*      out4 = reinterpret_cast<float4*>(ea_out)   + (size_t)e0 * 4;
#pragma unroll
  for (int q = 0; q < 4; ++q) {
    int fi = q * 256 + t;                 // local float4 index in [0,1024)
    float mm = smask[fi >> 2];
    float4 v = make_float4(0.f, 0.f, 0.f, 0.f);
    if (mm != 0.0f) v = ea4[fi];
    out4[fi] = v;
  }
}

// ---------------------------------------------------------------------------
extern "C" void kernel_launch(void* const* d_in, const int* in_sizes, int n_in,
                              void* d_out, int out_size, void* d_ws, size_t ws_size,
                              hipStream_t stream) {
  const float* x  = (const float*)d_in[0];
  const int*   ei = (const int*)d_in[1];
  const float* ea = (const float*)d_in[2];
  // d_in[3] = batch (unused: graphs contiguous & equal size)
  const float* W  = (const float*)d_in[4];
  const float* bb = (const float*)d_in[5];

  float* out       = (float*)d_out;
  float* xout      = out + OFF_XOUT;
  float* ei_out    = out + OFF_EI;
  float* ea_out    = out + OFF_EA;
  float* batch_out = out + OFF_BATCH;
  float* perm_out  = out + OFF_PERM;
  float* score_out = out + OFF_SCORE;
  float* emask_out = out + OFF_EMASK;

  int*    node_map = (int*)d_ws;                          // 256 KB
  double* dots     = (double*)((int*)d_ws + WS_DOTS_OFF); // 512 KB @ +256KB

  score_kernel <<<NTOT / 4, 256, 0, stream>>>(x, W, bb, score_out, dots);
  topk_kernel  <<<BGRAPH, 1024, 0, stream>>>(dots, perm_out, batch_out, node_map);
  gather_kernel<<<(BGRAPH * KSEL) / 4, 256, 0, stream>>>(x, perm_out, score_out, xout);
  edge_kernel  <<<EDG / 256, 256, 0, stream>>>(ei, node_map, ea, ei_out, emask_out, ea_out);
}

// Round 7
// 106.361 us; speedup vs baseline: 1.2883x; 1.0572x over previous
//
#include <hip/hip_runtime.h>
#include <math.h>

// Problem constants (match reference)
#define BGRAPH 64
#define N_PER  1024
#define KSEL   512
#define NTOT   65536       // BGRAPH * N_PER
#define EDG    2097152
#define FIN    256
#define FE     16

// d_out flat layout (float32 elements), reference tuple order:
#define OFF_XOUT   0
#define OFF_EI     8388608
#define OFF_EA     12582912
#define OFF_BATCH  46137344
#define OFF_PERM   46170112
#define OFF_SCORE  46202880
#define OFF_EMASK  46268416

// d_ws layout: [0,256KB) node_map (int[65536]); [256KB,768KB) dots (double[65536])
#define WS_DOTS_OFF 65536   // in ints

// ---------------------------------------------------------------------------
// Kernel 1 (FROZEN, verified absmax 128 over 5 passes): z = dot(x,W)+b in f64
// as rank key; value output via monotone-equivalent f32 tanhf.
__global__ __launch_bounds__(256) void score_kernel(
    const float* __restrict__ x, const float* __restrict__ W,
    const float* __restrict__ bptr, float* __restrict__ score_out,
    double* __restrict__ dot_out) {
  int wave = threadIdx.x >> 6;
  int lane = threadIdx.x & 63;
  int node = blockIdx.x * 4 + wave;
  const float4* xr = reinterpret_cast<const float4*>(x + (size_t)node * FIN);
  const float4* wr = reinterpret_cast<const float4*>(W);
  float4 xv = xr[lane];
  float4 wv = wr[lane];
  double p = (double)xv.x * (double)wv.x + (double)xv.y * (double)wv.y +
             (double)xv.z * (double)wv.z + (double)xv.w * (double)wv.w;
#pragma unroll
  for (int off = 32; off >= 1; off >>= 1) p += __shfl_xor(p, off, 64);
  if (lane == 0) {
    double z = p + (double)bptr[0];
    dot_out[node]   = z;
    score_out[node] = tanhf((float)z);   // MULTIPLIER == 1.0
  }
}

// ---------------------------------------------------------------------------
// Kernel 2 (FROZEN): per-graph hybrid bitonic sort of (f64 dot, idx).
// j<=32 via __shfl_xor (no barrier), j>=64 via LDS. Desc key, ties idx-asc.
__global__ __launch_bounds__(1024) void topk_kernel(
    const double* __restrict__ dots, float* __restrict__ perm_out,
    float* __restrict__ batch_out, int* __restrict__ node_map) {
  __shared__ double sk[N_PER];
  __shared__ int    si[N_PER];
  int b = blockIdx.x;
  int t = threadIdx.x;
  int base = b * N_PER;
  double key = dots[base + t];
  int    idx = t;
  node_map[base + t] = -1;   // block owns exactly its graph's slice
  for (int k = 2; k <= N_PER; k <<= 1) {
    for (int j = k >> 1; j > 0; j >>= 1) {
      bool lower = (t & j) == 0;
      bool dirUp = (t & k) == 0;
      double okey; int oidx;
      if (j >= 64) {
        sk[t] = key; si[t] = idx;
        __syncthreads();
        okey = sk[t ^ j]; oidx = si[t ^ j];
        __syncthreads();
      } else {
        okey = __shfl_xor(key, j, 64);
        oidx = __shfl_xor(idx, j, 64);
      }
      bool own_prec = (key > okey) || (key == okey && idx < oidx);
      bool want_prec = (lower == dirUp);
      if (own_prec != want_prec) { key = okey; idx = oidx; }
    }
  }
  if (t < KSEL) {
    int g   = base + idx;          // global node id
    int gid = b * KSEL + t;        // remapped id (rank order)
    perm_out[gid]  = (float)g;
    batch_out[gid] = (float)b;
    node_map[g]    = gid;
  }
}

// ---------------------------------------------------------------------------
// Kernel 3 (FROZEN): x_out[r] = x[perm[r]] * score[perm[r]]. One wave per row;
// x rows are L3-resident from the score pass (R5: tail FETCH showed ~L3 hits).
__global__ __launch_bounds__(256) void gather_kernel(
    const float* __restrict__ x, const float* __restrict__ perm_f,
    const float* __restrict__ score, float* __restrict__ xout) {
  int wave = threadIdx.x >> 6;
  int lane = threadIdx.x & 63;
  int r = blockIdx.x * 4 + wave;
  int g = (int)perm_f[r];           // exact (<= 65535)
  float s = score[g];
  float4 v = reinterpret_cast<const float4*>(x + (size_t)g * FIN)[lane];
  float4 o;
  o.x = v.x * s; o.y = v.y * s; o.z = v.z * s; o.w = v.w * s;
  reinterpret_cast<float4*>(xout + (size_t)r * FIN)[lane] = o;
}

// ---------------------------------------------------------------------------
// Kernel 4a: edge mask + remap ONLY. No LDS, no barrier — the dependent
// gather chain (ei -> node_map) no longer gates the byte-heavy attr copy.
// 4 edges/thread, every global access a 16-B vector op.
__global__ __launch_bounds__(256) void edgeA_kernel(
    const int* __restrict__ ei, const int* __restrict__ node_map,
    float* __restrict__ ei_out, float* __restrict__ emask_out) {
  int t = blockIdx.x * 256 + threadIdx.x;   // handles edges 4t..4t+3
  int4 r4 = reinterpret_cast<const int4*>(ei)[t];
  int4 c4 = reinterpret_cast<const int4*>(ei + EDG)[t];
  int nr0 = node_map[r4.x], nr1 = node_map[r4.y];
  int nr2 = node_map[r4.z], nr3 = node_map[r4.w];
  int nc0 = node_map[c4.x], nc1 = node_map[c4.y];
  int nc2 = node_map[c4.z], nc3 = node_map[c4.w];
  bool m0 = (nr0 >= 0) && (nc0 >= 0);
  bool m1 = (nr1 >= 0) && (nc1 >= 0);
  bool m2 = (nr2 >= 0) && (nc2 >= 0);
  bool m3 = (nr3 >= 0) && (nc3 >= 0);
  float4 ro = make_float4(m0 ? (float)nr0 : -1.0f, m1 ? (float)nr1 : -1.0f,
                          m2 ? (float)nr2 : -1.0f, m3 ? (float)nr3 : -1.0f);
  float4 co = make_float4(m0 ? (float)nc0 : -1.0f, m1 ? (float)nc1 : -1.0f,
                          m2 ? (float)nc2 : -1.0f, m3 ? (float)nc3 : -1.0f);
  float4 mo = make_float4(m0 ? 1.0f : 0.0f, m1 ? 1.0f : 0.0f,
                          m2 ? 1.0f : 0.0f, m3 ? 1.0f : 0.0f);
  reinterpret_cast<float4*>(ei_out)[t]       = ro;
  reinterpret_cast<float4*>(ei_out + EDG)[t] = co;
  reinterpret_cast<float4*>(emask_out)[t]    = mo;
}

// ---------------------------------------------------------------------------
// Kernel 4b: ea_new = emask ? edge_attr : 0. Pure streaming: 512 edges/block,
// 8 independent float4 slots per thread (static-indexed arrays -> registers,
// all 8 loads in flight). emask read from global (just written -> cache-hot).
// Reads of ea predicated (~75% of 128 MB skipped); stores unconditional
// (output poisoned). No LDS, no barrier.
__global__ __launch_bounds__(256) void edgeB_kernel(
    const float* __restrict__ ea, const float* __restrict__ emask,
    float* __restrict__ ea_out) {
  int t = threadIdx.x;
  int f0 = blockIdx.x * 2048;     // block covers float4 units [f0, f0+2048)
  const float4* ea4 = reinterpret_cast<const float4*>(ea);
  float4*      out4 = reinterpret_cast<float4*>(ea_out);
  float mm[8];
#pragma unroll
  for (int q = 0; q < 8; ++q) {
    int fi = f0 + q * 256 + t;
    mm[q] = emask[fi >> 2];
  }
  float4 v[8];
#pragma unroll
  for (int q = 0; q < 8; ++q) {
    int fi = f0 + q * 256 + t;
    v[q] = make_float4(0.f, 0.f, 0.f, 0.f);
    if (mm[q] != 0.0f) v[q] = ea4[fi];
  }
#pragma unroll
  for (int q = 0; q < 8; ++q) {
    int fi = f0 + q * 256 + t;
    out4[fi] = v[q];
  }
}

// ---------------------------------------------------------------------------
extern "C" void kernel_launch(void* const* d_in, const int* in_sizes, int n_in,
                              void* d_out, int out_size, void* d_ws, size_t ws_size,
                              hipStream_t stream) {
  const float* x  = (const float*)d_in[0];
  const int*   ei = (const int*)d_in[1];
  const float* ea = (const float*)d_in[2];
  // d_in[3] = batch (unused: graphs contiguous & equal size)
  const float* W  = (const float*)d_in[4];
  const float* bb = (const float*)d_in[5];

  float* out       = (float*)d_out;
  float* xout      = out + OFF_XOUT;
  float* ei_out    = out + OFF_EI;
  float* ea_out    = out + OFF_EA;
  float* batch_out = out + OFF_BATCH;
  float* perm_out  = out + OFF_PERM;
  float* score_out = out + OFF_SCORE;
  float* emask_out = out + OFF_EMASK;

  int*    node_map = (int*)d_ws;                          // 256 KB
  double* dots     = (double*)((int*)d_ws + WS_DOTS_OFF); // 512 KB @ +256KB

  score_kernel <<<NTOT / 4, 256, 0, stream>>>(x, W, bb, score_out, dots);
  topk_kernel  <<<BGRAPH, 1024, 0, stream>>>(dots, perm_out, batch_out, node_map);
  gather_kernel<<<(BGRAPH * KSEL) / 4, 256, 0, stream>>>(x, perm_out, score_out, xout);
  edgeA_kernel <<<EDG / 4 / 256, 256, 0, stream>>>(ei, node_map, ei_out, emask_out);
  edgeB_kernel <<<(EDG * 4) / 2048, 256, 0, stream>>>(ea, emask_out, ea_out);
}